// Round 6
// baseline (528.298 us; speedup 1.0000x reference)
//
#include <hip/hip_runtime.h>
#include <hip/hip_bf16.h>

#define NNODES 100000
#define NEDGES 1600000
#define EPSBN 1e-5f

// CSR build via bucketed counting sort
#define BKT_SHIFT 9
#define NODES_PER_BKT 512
#define NBKT 196
#define NCHUNK 256
#define CHUNK 6250
#define SRC_MASK 0x1FFFF
#define NSLOT 64

typedef unsigned short u16;
typedef unsigned int u32;
typedef __bf16 bf16x8 __attribute__((ext_vector_type(8)));
typedef float floatx4 __attribute__((ext_vector_type(4)));
typedef unsigned int uint4v __attribute__((ext_vector_type(4)));
typedef float float4v __attribute__((ext_vector_type(4)));

__device__ __forceinline__ u16 f2bf(float f) {
    unsigned int u = __float_as_uint(f);
    unsigned int r = (u + 0x7fffu + ((u >> 16) & 1u)) >> 16;
    return (u16)r;
}
__device__ __forceinline__ float bflo(unsigned int u) { return __uint_as_float(u << 16); }
__device__ __forceinline__ float bfhi(unsigned int u) { return __uint_as_float(u & 0xffff0000u); }

// nontemporal vector stores: keep streamed outputs from evicting the gather table in L2
__device__ __forceinline__ void nt_store_u4(void* p, uint4 v) {
    uint4v t; t.x = v.x; t.y = v.y; t.z = v.z; t.w = v.w;
    __builtin_nontemporal_store(t, (uint4v*)p);
}
__device__ __forceinline__ void nt_store_f4(float* p, float4 v) {
    float4v t; t.x = v.x; t.y = v.y; t.z = v.z; t.w = v.w;
    __builtin_nontemporal_store(t, (float4v*)p);
}

// ---------------- CSR build: bucketed counting sort ----------------

__global__ __launch_bounds__(256) void k_hist(const int* __restrict__ ei, int* __restrict__ histT) {
    __shared__ int h[NBKT];
    int tid = threadIdx.x;
    if (tid < NBKT) h[tid] = 0;
    __syncthreads();
    int base = blockIdx.x * CHUNK;
    for (int e = base + tid; e < base + CHUNK; e += 256) {
        int d = ei[NEDGES + e];
        atomicAdd(&h[d >> BKT_SHIFT], 1);
    }
    __syncthreads();
    if (tid < NBKT) histT[tid * NCHUNK + blockIdx.x] = h[tid];
}

__global__ __launch_bounds__(256) void k_bbase(const int* __restrict__ histT, int* __restrict__ bbase,
                                               int* __restrict__ rowptr) {
    __shared__ int sdata[256];
    int tid = threadIdx.x;
    int s = 0;
    if (tid < NBKT) {
        for (int g = 0; g < NCHUNK; ++g) s += histT[tid * NCHUNK + g];
    }
    int val = s;
    sdata[tid] = val;
    __syncthreads();
    for (int off = 1; off < 256; off <<= 1) {
        int add = (tid >= off) ? sdata[tid - off] : 0;
        __syncthreads();
        val += add;
        sdata[tid] = val;
        __syncthreads();
    }
    if (tid < NBKT) bbase[tid] = val - s;
    if (tid == 0) { bbase[NBKT] = NEDGES; rowptr[NNODES] = NEDGES; }
}

__global__ __launch_bounds__(256) void k_bscan(const int* __restrict__ histT, const int* __restrict__ bbase,
                                               int* __restrict__ offT) {
    __shared__ int sdata[256];
    int b = blockIdx.x;
    int g = threadIdx.x;
    int v = histT[b * NCHUNK + g];
    int val = v;
    sdata[g] = val;
    __syncthreads();
    for (int off = 1; off < 256; off <<= 1) {
        int add = (g >= off) ? sdata[g - off] : 0;
        __syncthreads();
        val += add;
        sdata[g] = val;
        __syncthreads();
    }
    offT[b * NCHUNK + g] = bbase[b] + (val - v);
}

__global__ __launch_bounds__(256) void k_scatter(const int* __restrict__ ei, const int* __restrict__ offT,
                                                 u32* __restrict__ rec) {
    __shared__ int cur[NBKT];
    int tid = threadIdx.x;
    if (tid < NBKT) cur[tid] = offT[tid * NCHUNK + blockIdx.x];
    __syncthreads();
    int base = blockIdx.x * CHUNK;
    for (int e = base + tid; e < base + CHUNK; e += 256) {
        int s = ei[e];
        int d = ei[NEDGES + e];
        int b = d >> BKT_SHIFT;
        int p = atomicAdd(&cur[b], 1);
        rec[p] = ((u32)(d & (NODES_PER_BKT - 1)) << 17) | (u32)s;
    }
}

__global__ __launch_bounds__(256) void k_bfill(const u32* __restrict__ rec, const int* __restrict__ bbase,
                                               int* __restrict__ rowptr, float* __restrict__ dinv,
                                               int* __restrict__ colsrc) {
    __shared__ int cnt[NODES_PER_BKT];
    __shared__ int sdata[256];
    int tid = threadIdx.x;
    int b = blockIdx.x;
    int n0 = b * NODES_PER_BKT;
    int r0 = bbase[b], r1 = bbase[b + 1];
    cnt[2 * tid] = 0;
    cnt[2 * tid + 1] = 0;
    __syncthreads();
    for (int r = r0 + tid; r < r1; r += 256) {
        atomicAdd(&cnt[rec[r] >> 17], 1);
    }
    __syncthreads();
    int c0 = cnt[2 * tid], c1 = cnt[2 * tid + 1];
    int ps = c0 + c1;
    int val = ps;
    sdata[tid] = val;
    __syncthreads();
    for (int off = 1; off < 256; off <<= 1) {
        int add = (tid >= off) ? sdata[tid - off] : 0;
        __syncthreads();
        val += add;
        sdata[tid] = val;
        __syncthreads();
    }
    int e0 = val - ps;
    int e1 = e0 + c0;
    int na = n0 + 2 * tid, nb2 = n0 + 2 * tid + 1;
    if (na < NNODES) {
        rowptr[na] = r0 + e0;
        dinv[na] = rsqrtf((float)(c0 + 1));
    }
    if (nb2 < NNODES) {
        rowptr[nb2] = r0 + e1;
        dinv[nb2] = rsqrtf((float)(c1 + 1));
    }
    cnt[2 * tid] = r0 + e0;
    cnt[2 * tid + 1] = r0 + e1;
    __syncthreads();
    for (int r = r0 + tid; r < r1; r += 256) {
        u32 u = rec[r];
        int p = atomicAdd(&cnt[u >> 17], 1);
        colsrc[p] = (int)(u & SRC_MASK);
    }
}

// ---------------- pack all W into B-fragment layout ----------------

template <int COUT>
__device__ __forceinline__ void packone(const float* __restrict__ W, u16* __restrict__ Wp, int f) {
    constexpr int CT = COUT / 16;
    if (f >= 4 * CT * 64) return;
    int ks = f / (CT * 64);
    int ct = (f / 64) % CT;
    int lane = f % 64;
    int quad = lane >> 4, mm = lane & 15;
#pragma unroll
    for (int j = 0; j < 8; ++j) {
        float v = W[(size_t)(ks * 32 + quad * 8 + j) * COUT + ct * 16 + mm];
        Wp[(size_t)f * 8 + j] = f2bf(v);
    }
}

__global__ __launch_bounds__(256) void k_packW_all(const float* __restrict__ W1, const float* __restrict__ W2,
                                                   const float* __restrict__ W3, u16* __restrict__ Wp1,
                                                   u16* __restrict__ Wp2, u16* __restrict__ Wp3) {
    int b = blockIdx.x;
    if (b < 8) packone<128>(W1, Wp1, b * 256 + threadIdx.x);
    else if (b < 16) packone<128>(W2, Wp2, (b - 8) * 256 + threadIdx.x);
    else packone<64>(W3, Wp3, (b - 16) * 256 + threadIdx.x);
}

// ---------------- MFMA GEMM (fp32 or bf16 input, optional fused BN affine + ReLU + h-write) ----------------
// Bout[r][c] = bf16( dinv[r] * sum_k act(X[r][k])*W[k][c] ),  act = relu(scale*x+shift) if AFFINE

template <int COUT, bool AFFINE, bool WRITEH, bool BF16IN>
__global__ __launch_bounds__(256) void k_mfma_gemm(const void* __restrict__ Xv, const u16* __restrict__ Wp,
                                                   const float* __restrict__ dinv,
                                                   const float* __restrict__ scale, const float* __restrict__ shift,
                                                   u16* __restrict__ Bout, float* __restrict__ Hout) {
    constexpr int CT = COUT / 16;
    const int wave = threadIdx.x >> 6;
    const int lane = threadIdx.x & 63;
    const int quad = lane >> 4;
    const int m = lane & 15;
    const int rowbase = blockIdx.x * 64 + wave * 16;
    const int arow = rowbase + m;
    const bool rv = arow < NNODES;
    floatx4 acc[CT];
#pragma unroll
    for (int ct = 0; ct < CT; ++ct) acc[ct] = floatx4{0.f, 0.f, 0.f, 0.f};
#pragma unroll
    for (int ks = 0; ks < 4; ++ks) {
        const int k0 = ks * 32 + quad * 8;
        float4 xa = make_float4(0.f, 0.f, 0.f, 0.f), xb = xa;
        if (rv) {
            if (BF16IN) {
                uint4 q = *(const uint4*)((const u16*)Xv + (size_t)arow * 128 + k0);
                xa.x = bflo(q.x); xa.y = bfhi(q.x); xa.z = bflo(q.y); xa.w = bfhi(q.y);
                xb.x = bflo(q.z); xb.y = bfhi(q.z); xb.z = bflo(q.w); xb.w = bfhi(q.w);
            } else {
                xa = *(const float4*)((const float*)Xv + (size_t)arow * 128 + k0);
                xb = *(const float4*)((const float*)Xv + (size_t)arow * 128 + k0 + 4);
            }
        }
        if (AFFINE) {
            float4 sa = *(const float4*)(scale + k0), sb = *(const float4*)(scale + k0 + 4);
            float4 ha = *(const float4*)(shift + k0), hb = *(const float4*)(shift + k0 + 4);
            xa.x = fmaxf(fmaf(xa.x, sa.x, ha.x), 0.f);
            xa.y = fmaxf(fmaf(xa.y, sa.y, ha.y), 0.f);
            xa.z = fmaxf(fmaf(xa.z, sa.z, ha.z), 0.f);
            xa.w = fmaxf(fmaf(xa.w, sa.w, ha.w), 0.f);
            xb.x = fmaxf(fmaf(xb.x, sb.x, hb.x), 0.f);
            xb.y = fmaxf(fmaf(xb.y, sb.y, hb.y), 0.f);
            xb.z = fmaxf(fmaf(xb.z, sb.z, hb.z), 0.f);
            xb.w = fmaxf(fmaf(xb.w, sb.w, hb.w), 0.f);
        }
        if (WRITEH && rv) {
            nt_store_f4(Hout + (size_t)arow * 128 + k0, xa);
            nt_store_f4(Hout + (size_t)arow * 128 + k0 + 4, xb);
        }
        union { u16 h[8]; bf16x8 v; } ua;
        ua.h[0] = f2bf(xa.x); ua.h[1] = f2bf(xa.y); ua.h[2] = f2bf(xa.z); ua.h[3] = f2bf(xa.w);
        ua.h[4] = f2bf(xb.x); ua.h[5] = f2bf(xb.y); ua.h[6] = f2bf(xb.z); ua.h[7] = f2bf(xb.w);
#pragma unroll
        for (int ct = 0; ct < CT; ++ct) {
            uint4 bv = *(const uint4*)(Wp + ((size_t)(ks * CT + ct) * 64 + lane) * 8);
            bf16x8 b = *(const bf16x8*)&bv;
            acc[ct] = __builtin_amdgcn_mfma_f32_16x16x32_bf16(ua.v, b, acc[ct], 0, 0, 0);
        }
    }
    float dv[4];
#pragma unroll
    for (int reg = 0; reg < 4; ++reg) {
        int r = rowbase + quad * 4 + reg;
        dv[reg] = (r < NNODES) ? dinv[r] : 0.f;
    }
#pragma unroll
    for (int ct = 0; ct < CT; ++ct) {
#pragma unroll
        for (int reg = 0; reg < 4; ++reg) {
            int r = rowbase + quad * 4 + reg;
            if (r < NNODES) Bout[(size_t)r * COUT + ct * 16 + m] = f2bf(dv[reg] * acc[ct][reg]);
        }
    }
}

// ---------------- Aggregation, XCD-aware channel-half split ----------------
// A Bm row (256B) = two 128B cache lines (ch 0-63 | ch 64-127). Blocks dispatch
// round-robin to the 8 XCDs (blockIdx%8); XCDs 0-3 aggregate half 0, XCDs 4-7
// half 1 -> each XCD's gather working set is 12.8MB instead of 25.6MB, and the
// split is line-aligned so no fetched byte is wasted.
// Out[d][c] = dinv[d]*(B[d][c] + sum_s B[s][c]) + bias[c]; logical index 0 = self-loop.

template <bool STATS, bool OUTB>
__global__ __launch_bounds__(256) void k_agg128h(const u16* __restrict__ Bm, const float* __restrict__ dinv,
                                                 const int* __restrict__ rowptr, const int* __restrict__ colsrc,
                                                 const float* __restrict__ bias, void* __restrict__ Outv,
                                                 float* __restrict__ slots) {
    __shared__ float sO[4][64];
    const int bid = blockIdx.x;
    const int half = (bid & 7) >> 2;                 // XCD 0-3 -> half 0, XCD 4-7 -> half 1
    const int nodeblk = (bid >> 3) * 4 + (bid & 3);  // 0..24999, each covered once per half
    const int wave = threadIdx.x >> 6;
    const int node = nodeblk * 4 + wave;
    const int lane = threadIdx.x & 63;
    const int g = lane >> 3;     // 8 edge slots
    const int c8 = lane & 7;     // uint4 chunk within the 128B half-row
    const uint4* Bq = (const uint4*)Bm;  // row stride = 16 uint4
    const int hoff = half * 8 + c8;
    float a0[8], a1[8];
#pragma unroll
    for (int j = 0; j < 8; ++j) { a0[j] = 0.f; a1[j] = 0.f; }
    const int beg = rowptr[node];
    const int L = rowptr[node + 1] - beg + 1;  // edges + self
    for (int it = 0; it < L; it += 16) {
        int i0 = it + g, i1 = it + 8 + g;
        float w0 = (i0 < L) ? 1.f : 0.f;
        float w1 = (i1 < L) ? 1.f : 0.f;
        i0 = min(i0, L - 1);
        i1 = min(i1, L - 1);
        int s0 = __builtin_nontemporal_load(&colsrc[beg + max(i0, 1) - 1]);
        int s1 = __builtin_nontemporal_load(&colsrc[beg + max(i1, 1) - 1]);
        if (i0 == 0) s0 = node;  // self (only it==0, g==0)
        uint4 q0 = Bq[(size_t)s0 * 16 + hoff];
        uint4 q1 = Bq[(size_t)s1 * 16 + hoff];
        a0[0] += w0 * bflo(q0.x); a0[1] += w0 * bfhi(q0.x);
        a0[2] += w0 * bflo(q0.y); a0[3] += w0 * bfhi(q0.y);
        a0[4] += w0 * bflo(q0.z); a0[5] += w0 * bfhi(q0.z);
        a0[6] += w0 * bflo(q0.w); a0[7] += w0 * bfhi(q0.w);
        a1[0] += w1 * bflo(q1.x); a1[1] += w1 * bfhi(q1.x);
        a1[2] += w1 * bflo(q1.y); a1[3] += w1 * bfhi(q1.y);
        a1[4] += w1 * bflo(q1.z); a1[5] += w1 * bfhi(q1.z);
        a1[6] += w1 * bflo(q1.w); a1[7] += w1 * bfhi(q1.w);
    }
    const float dv = dinv[node];
    float o[8];
#pragma unroll
    for (int j = 0; j < 8; ++j) {
        float s = a0[j] + a1[j];
        s += __shfl_xor(s, 8);
        s += __shfl_xor(s, 16);
        s += __shfl_xor(s, 32);
        o[j] = dv * s + bias[half * 64 + c8 * 8 + j];
    }
    if (g == 0) {
        if (OUTB) {
            u16* OutB = (u16*)Outv;
            union { u32 w[4]; uint4 q; } p;
            p.w[0] = (u32)f2bf(o[0]) | ((u32)f2bf(o[1]) << 16);
            p.w[1] = (u32)f2bf(o[2]) | ((u32)f2bf(o[3]) << 16);
            p.w[2] = (u32)f2bf(o[4]) | ((u32)f2bf(o[5]) << 16);
            p.w[3] = (u32)f2bf(o[6]) | ((u32)f2bf(o[7]) << 16);
            nt_store_u4(OutB + (size_t)node * 128 + half * 64 + c8 * 8, p.q);
        } else {
            float* Out = (float*)Outv;
            nt_store_f4(Out + (size_t)node * 128 + half * 64 + c8 * 8, make_float4(o[0], o[1], o[2], o[3]));
            nt_store_f4(Out + (size_t)node * 128 + half * 64 + c8 * 8 + 4, make_float4(o[4], o[5], o[6], o[7]));
        }
        if (STATS) {
#pragma unroll
            for (int j = 0; j < 8; ++j) sO[wave][c8 * 8 + j] = o[j];
        }
    }
    if (STATS) {
        __syncthreads();
        if (threadIdx.x < 64) {
            float s = 0.f, q = 0.f;
#pragma unroll
            for (int wv = 0; wv < 4; ++wv) {
                float v = sO[wv][threadIdx.x];
                s += v;
                q += v * v;
            }
            float* slot = slots + (size_t)(bid & (NSLOT - 1)) * 256;
            atomicAdd(&slot[half * 64 + threadIdx.x], s);
            atomicAdd(&slot[128 + half * 64 + threadIdx.x], q);
        }
    }
}

__global__ __launch_bounds__(256) void k_agg64v(const u16* __restrict__ Bm, const float* __restrict__ dinv,
                                                const int* __restrict__ rowptr, const int* __restrict__ colsrc,
                                                const float* __restrict__ bias, float* __restrict__ Out) {
    const int node = blockIdx.x * 4 + (threadIdx.x >> 6);
    const int lane = threadIdx.x & 63;
    const int g = lane >> 3;    // 0..7 edge slots
    const int c8 = lane & 7;    // channels c8*8 .. +7
    const uint4* Bq = (const uint4*)Bm;
    float a0[8], a1[8];
#pragma unroll
    for (int j = 0; j < 8; ++j) { a0[j] = 0.f; a1[j] = 0.f; }
    const int beg = rowptr[node];
    const int L = rowptr[node + 1] - beg + 1;
    for (int it = 0; it < L; it += 16) {
        int i0 = it + g, i1 = it + 8 + g;
        float w0 = (i0 < L) ? 1.f : 0.f;
        float w1 = (i1 < L) ? 1.f : 0.f;
        i0 = min(i0, L - 1);
        i1 = min(i1, L - 1);
        int s0 = __builtin_nontemporal_load(&colsrc[beg + max(i0, 1) - 1]);
        int s1 = __builtin_nontemporal_load(&colsrc[beg + max(i1, 1) - 1]);
        if (i0 == 0) s0 = node;
        uint4 q0 = Bq[(size_t)s0 * 8 + c8];
        uint4 q1 = Bq[(size_t)s1 * 8 + c8];
        a0[0] += w0 * bflo(q0.x); a0[1] += w0 * bfhi(q0.x);
        a0[2] += w0 * bflo(q0.y); a0[3] += w0 * bfhi(q0.y);
        a0[4] += w0 * bflo(q0.z); a0[5] += w0 * bfhi(q0.z);
        a0[6] += w0 * bflo(q0.w); a0[7] += w0 * bfhi(q0.w);
        a1[0] += w1 * bflo(q1.x); a1[1] += w1 * bfhi(q1.x);
        a1[2] += w1 * bflo(q1.y); a1[3] += w1 * bfhi(q1.y);
        a1[4] += w1 * bflo(q1.z); a1[5] += w1 * bfhi(q1.z);
        a1[6] += w1 * bflo(q1.w); a1[7] += w1 * bfhi(q1.w);
    }
    const float dv = dinv[node];
    float o[8];
#pragma unroll
    for (int j = 0; j < 8; ++j) {
        float s = a0[j] + a1[j];
        s += __shfl_xor(s, 8);
        s += __shfl_xor(s, 16);
        s += __shfl_xor(s, 32);
        o[j] = dv * s + bias[c8 * 8 + j];
    }
    if (g == 0) {
        nt_store_f4(Out + (size_t)node * 64 + c8 * 8, make_float4(o[0], o[1], o[2], o[3]));
        nt_store_f4(Out + (size_t)node * 64 + c8 * 8 + 4, make_float4(o[4], o[5], o[6], o[7]));
    }
}

// ---------------- BN finalize: reduce slots -> scale/shift ----------------

__global__ void k_bn_final(const float* __restrict__ slots, const float* __restrict__ g,
                           const float* __restrict__ be, float* __restrict__ scale, float* __restrict__ shift) {
    int c = threadIdx.x;  // 128 threads
    float s = 0.f, q = 0.f;
    for (int k = 0; k < NSLOT; ++k) {
        s += slots[(size_t)k * 256 + c];
        q += slots[(size_t)k * 256 + 128 + c];
    }
    float mean = s * (1.0f / NNODES);
    float var = q * (1.0f / NNODES) - mean * mean;
    float istd = rsqrtf(var + EPSBN);
    float sc = g[c] * istd;
    scale[c] = sc;
    shift[c] = be[c] - sc * mean;
}

// ---------------- launch ----------------

extern "C" void kernel_launch(void* const* d_in, const int* in_sizes, int n_in,
                              void* d_out, int out_size, void* d_ws, size_t ws_size,
                              hipStream_t stream) {
    const float* x   = (const float*)d_in[0];
    const float* W1  = (const float*)d_in[1];
    const float* b1  = (const float*)d_in[2];
    const float* g1  = (const float*)d_in[3];
    const float* be1 = (const float*)d_in[4];
    const float* W2  = (const float*)d_in[5];
    const float* b2  = (const float*)d_in[6];
    const float* g2  = (const float*)d_in[7];
    const float* be2 = (const float*)d_in[8];
    const float* W3  = (const float*)d_in[9];
    const float* b3  = (const float*)d_in[10];
    const int* ei    = (const int*)d_in[11];

    float* out_h = (float*)d_out;                        // [N,128] h2
    float* out_o = (float*)d_out + (size_t)NNODES * 128; // [N,64]  conv3 out

    char* w = (char*)d_ws;
    u16* A16 = (u16*)w;        w += (size_t)NNODES * 128 * 2;   // bf16 post-agg activations
    u16* Bm = (u16*)w;         w += (size_t)NNODES * 128 * 2;   // bf16 messages
    float* dinv = (float*)w;   w += (size_t)NNODES * 4;
    int* rowptr = (int*)w;     w += (size_t)(NNODES + 32) * 4;
    int* colsrc = (int*)w;     w += (size_t)(NEDGES + 8) * 4;   // +pad for clamped tail reads
    int* bbase = (int*)w;      w += (NBKT + 4) * 4;
    float* slots1 = (float*)w; w += (size_t)NSLOT * 256 * 4;
    float* slots2 = (float*)w; w += (size_t)NSLOT * 256 * 4;
    float* scale = (float*)w;  w += 128 * 4;
    float* shift = (float*)w;  w += 128 * 4;
    u16* Wp1 = (u16*)w;        w += 128 * 128 * 2;
    u16* Wp2 = (u16*)w;        w += 128 * 128 * 2;
    u16* Wp3 = (u16*)w;        w += 128 * 64 * 2;

    // Build-phase scratch aliased onto buffers dead until layer 1:
    u32* rec  = (u32*)A16;                      // [NEDGES] (25.6MB >= 6.4MB needed)
    int* histT = (int*)Bm;                      // [NBKT*NCHUNK]
    int* offT  = (int*)Bm + NBKT * NCHUNK;      // [NBKT*NCHUNK]

    hipMemsetAsync(slots1, 0, (size_t)2 * NSLOT * 256 * 4, stream);

    k_packW_all<<<20, 256, 0, stream>>>(W1, W2, W3, Wp1, Wp2, Wp3);

    // CSR build
    k_hist<<<NCHUNK, 256, 0, stream>>>(ei, histT);
    k_bbase<<<1, 256, 0, stream>>>(histT, bbase, rowptr);
    k_bscan<<<NBKT, 256, 0, stream>>>(histT, bbase, offT);
    k_scatter<<<NCHUNK, 256, 0, stream>>>(ei, offT, rec);
    k_bfill<<<NBKT, 256, 0, stream>>>(rec, bbase, rowptr, dinv, colsrc);

    const int GB = (NNODES + 63) / 64;   // 1563
    const int AB = NNODES / 4;           // 25000
    const int AB2 = 2 * AB;              // 50000 (2x: one per channel half)

    // Layer 1: x (fp32) -> Bm -> A16 bf16 (+stats1)
    k_mfma_gemm<128, false, false, false><<<GB, 256, 0, stream>>>(x, Wp1, dinv, nullptr, nullptr, Bm, nullptr);
    k_agg128h<true, true><<<AB2, 256, 0, stream>>>(Bm, dinv, rowptr, colsrc, b1, A16, slots1);
    k_bn_final<<<1, 128, 0, stream>>>(slots1, g1, be1, scale, shift);

    // Layer 2: A16 bf16 (BN1+ReLU inline) -> Bm -> A16 bf16 (+stats2)
    k_mfma_gemm<128, true, false, true><<<GB, 256, 0, stream>>>(A16, Wp2, dinv, scale, shift, Bm, nullptr);
    k_agg128h<true, true><<<AB2, 256, 0, stream>>>(Bm, dinv, rowptr, colsrc, b2, A16, slots2);
    k_bn_final<<<1, 128, 0, stream>>>(slots2, g2, be2, scale, shift);

    // Layer 3: A16 bf16 (BN2+ReLU inline, h2 written fp32 as byproduct) -> Bm64 -> out_o
    k_mfma_gemm<64, true, true, true><<<GB, 256, 0, stream>>>(A16, Wp3, dinv, scale, shift, Bm, out_h);
    k_agg64v<<<AB, 256, 0, stream>>>(Bm, dinv, rowptr, colsrc, b3, out_o);
}

// Round 7
// 450.501 us; speedup vs baseline: 1.1727x; 1.1727x over previous
//
#include <hip/hip_runtime.h>
#include <hip/hip_bf16.h>

#define NNODES 100000
#define NEDGES 1600000
#define EPSBN 1e-5f

// CSR build via bucketed counting sort
#define BKT_SHIFT 9
#define NODES_PER_BKT 512
#define NBKT 196
#define NCHUNK 256
#define CHUNK 6250
#define SRC_MASK 0x1FFFF
#define NSLOT 64

typedef unsigned short u16;
typedef unsigned int u32;
typedef __bf16 bf16x8 __attribute__((ext_vector_type(8)));
typedef float floatx4 __attribute__((ext_vector_type(4)));
typedef unsigned int uint4v __attribute__((ext_vector_type(4)));
typedef float float4v __attribute__((ext_vector_type(4)));

__device__ __forceinline__ u16 f2bf(float f) {
    unsigned int u = __float_as_uint(f);
    unsigned int r = (u + 0x7fffu + ((u >> 16) & 1u)) >> 16;
    return (u16)r;
}
__device__ __forceinline__ float bflo(unsigned int u) { return __uint_as_float(u << 16); }
__device__ __forceinline__ float bfhi(unsigned int u) { return __uint_as_float(u & 0xffff0000u); }

// nontemporal vector stores: keep streamed outputs from evicting the gather table in L2
__device__ __forceinline__ void nt_store_u4(void* p, uint4 v) {
    uint4v t; t.x = v.x; t.y = v.y; t.z = v.z; t.w = v.w;
    __builtin_nontemporal_store(t, (uint4v*)p);
}
__device__ __forceinline__ void nt_store_f4(float* p, float4 v) {
    float4v t; t.x = v.x; t.y = v.y; t.z = v.z; t.w = v.w;
    __builtin_nontemporal_store(t, (float4v*)p);
}

// ---------------- CSR build: bucketed counting sort ----------------

__global__ __launch_bounds__(256) void k_hist(const int* __restrict__ ei, int* __restrict__ histT) {
    __shared__ int h[NBKT];
    int tid = threadIdx.x;
    if (tid < NBKT) h[tid] = 0;
    __syncthreads();
    int base = blockIdx.x * CHUNK;
    for (int e = base + tid; e < base + CHUNK; e += 256) {
        int d = ei[NEDGES + e];
        atomicAdd(&h[d >> BKT_SHIFT], 1);
    }
    __syncthreads();
    if (tid < NBKT) histT[tid * NCHUNK + blockIdx.x] = h[tid];
}

// parallel per-bucket total (replaces the serial half of old k_bbase)
__global__ __launch_bounds__(256) void k_bsum(const int* __restrict__ histT, int* __restrict__ btot) {
    __shared__ int red[256];
    int b = blockIdx.x, t = threadIdx.x;
    red[t] = histT[b * NCHUNK + t];
    __syncthreads();
    for (int off = 128; off > 0; off >>= 1) {
        if (t < off) red[t] += red[t + off];
        __syncthreads();
    }
    if (t == 0) btot[b] = red[0];
}

// tiny single-block scan over 196 bucket totals
__global__ __launch_bounds__(256) void k_bbase2(const int* __restrict__ btot, int* __restrict__ bbase,
                                                int* __restrict__ rowptr) {
    __shared__ int sdata[256];
    int tid = threadIdx.x;
    int v = (tid < NBKT) ? btot[tid] : 0;
    int val = v;
    sdata[tid] = val;
    __syncthreads();
    for (int off = 1; off < 256; off <<= 1) {
        int add = (tid >= off) ? sdata[tid - off] : 0;
        __syncthreads();
        val += add;
        sdata[tid] = val;
        __syncthreads();
    }
    if (tid < NBKT) bbase[tid] = val - v;
    if (tid == 0) { bbase[NBKT] = NEDGES; rowptr[NNODES] = NEDGES; }
}

__global__ __launch_bounds__(256) void k_bscan(const int* __restrict__ histT, const int* __restrict__ bbase,
                                               int* __restrict__ offT) {
    __shared__ int sdata[256];
    int b = blockIdx.x;
    int g = threadIdx.x;
    int v = histT[b * NCHUNK + g];
    int val = v;
    sdata[g] = val;
    __syncthreads();
    for (int off = 1; off < 256; off <<= 1) {
        int add = (g >= off) ? sdata[g - off] : 0;
        __syncthreads();
        val += add;
        sdata[g] = val;
        __syncthreads();
    }
    offT[b * NCHUNK + g] = bbase[b] + (val - v);
}

__global__ __launch_bounds__(256) void k_scatter(const int* __restrict__ ei, const int* __restrict__ offT,
                                                 u32* __restrict__ rec) {
    __shared__ int cur[NBKT];
    int tid = threadIdx.x;
    if (tid < NBKT) cur[tid] = offT[tid * NCHUNK + blockIdx.x];
    __syncthreads();
    int base = blockIdx.x * CHUNK;
    for (int e = base + tid; e < base + CHUNK; e += 256) {
        int s = ei[e];
        int d = ei[NEDGES + e];
        int b = d >> BKT_SHIFT;
        int p = atomicAdd(&cur[b], 1);
        rec[p] = ((u32)(d & (NODES_PER_BKT - 1)) << 17) | (u32)s;
    }
}

__global__ __launch_bounds__(256) void k_bfill(const u32* __restrict__ rec, const int* __restrict__ bbase,
                                               int* __restrict__ rowptr, float* __restrict__ dinv,
                                               int* __restrict__ colsrc) {
    __shared__ int cnt[NODES_PER_BKT];
    __shared__ int sdata[256];
    int tid = threadIdx.x;
    int b = blockIdx.x;
    int n0 = b * NODES_PER_BKT;
    int r0 = bbase[b], r1 = bbase[b + 1];
    cnt[2 * tid] = 0;
    cnt[2 * tid + 1] = 0;
    __syncthreads();
    for (int r = r0 + tid; r < r1; r += 256) {
        atomicAdd(&cnt[rec[r] >> 17], 1);
    }
    __syncthreads();
    int c0 = cnt[2 * tid], c1 = cnt[2 * tid + 1];
    int ps = c0 + c1;
    int val = ps;
    sdata[tid] = val;
    __syncthreads();
    for (int off = 1; off < 256; off <<= 1) {
        int add = (tid >= off) ? sdata[tid - off] : 0;
        __syncthreads();
        val += add;
        sdata[tid] = val;
        __syncthreads();
    }
    int e0 = val - ps;
    int e1 = e0 + c0;
    int na = n0 + 2 * tid, nb2 = n0 + 2 * tid + 1;
    if (na < NNODES) {
        rowptr[na] = r0 + e0;
        dinv[na] = rsqrtf((float)(c0 + 1));
    }
    if (nb2 < NNODES) {
        rowptr[nb2] = r0 + e1;
        dinv[nb2] = rsqrtf((float)(c1 + 1));
    }
    cnt[2 * tid] = r0 + e0;
    cnt[2 * tid + 1] = r0 + e1;
    __syncthreads();
    for (int r = r0 + tid; r < r1; r += 256) {
        u32 u = rec[r];
        int p = atomicAdd(&cnt[u >> 17], 1);
        colsrc[p] = (int)(u & SRC_MASK);
    }
}

// ---------------- pack all W into B-fragment layout ----------------

template <int COUT>
__device__ __forceinline__ void packone(const float* __restrict__ W, u16* __restrict__ Wp, int f) {
    constexpr int CT = COUT / 16;
    if (f >= 4 * CT * 64) return;
    int ks = f / (CT * 64);
    int ct = (f / 64) % CT;
    int lane = f % 64;
    int quad = lane >> 4, mm = lane & 15;
#pragma unroll
    for (int j = 0; j < 8; ++j) {
        float v = W[(size_t)(ks * 32 + quad * 8 + j) * COUT + ct * 16 + mm];
        Wp[(size_t)f * 8 + j] = f2bf(v);
    }
}

__global__ __launch_bounds__(256) void k_packW_all(const float* __restrict__ W1, const float* __restrict__ W2,
                                                   const float* __restrict__ W3, u16* __restrict__ Wp1,
                                                   u16* __restrict__ Wp2, u16* __restrict__ Wp3) {
    int b = blockIdx.x;
    if (b < 8) packone<128>(W1, Wp1, b * 256 + threadIdx.x);
    else if (b < 16) packone<128>(W2, Wp2, (b - 8) * 256 + threadIdx.x);
    else packone<64>(W3, Wp3, (b - 16) * 256 + threadIdx.x);
}

// ---------------- MFMA GEMM (fp32 or bf16 input, optional fused BN affine + ReLU + h-write) ----------------
// Bout[r][c] = bf16( dinv[r] * sum_k act(X[r][k])*W[k][c] ),  act = relu(scale*x+shift) if AFFINE

template <int COUT, bool AFFINE, bool WRITEH, bool BF16IN>
__global__ __launch_bounds__(256) void k_mfma_gemm(const void* __restrict__ Xv, const u16* __restrict__ Wp,
                                                   const float* __restrict__ dinv,
                                                   const float* __restrict__ scale, const float* __restrict__ shift,
                                                   u16* __restrict__ Bout, float* __restrict__ Hout) {
    constexpr int CT = COUT / 16;
    const int wave = threadIdx.x >> 6;
    const int lane = threadIdx.x & 63;
    const int quad = lane >> 4;
    const int m = lane & 15;
    const int rowbase = blockIdx.x * 64 + wave * 16;
    const int arow = rowbase + m;
    const bool rv = arow < NNODES;
    floatx4 acc[CT];
#pragma unroll
    for (int ct = 0; ct < CT; ++ct) acc[ct] = floatx4{0.f, 0.f, 0.f, 0.f};
#pragma unroll
    for (int ks = 0; ks < 4; ++ks) {
        const int k0 = ks * 32 + quad * 8;
        float4 xa = make_float4(0.f, 0.f, 0.f, 0.f), xb = xa;
        if (rv) {
            if (BF16IN) {
                uint4 q = *(const uint4*)((const u16*)Xv + (size_t)arow * 128 + k0);
                xa.x = bflo(q.x); xa.y = bfhi(q.x); xa.z = bflo(q.y); xa.w = bfhi(q.y);
                xb.x = bflo(q.z); xb.y = bfhi(q.z); xb.z = bflo(q.w); xb.w = bfhi(q.w);
            } else {
                xa = *(const float4*)((const float*)Xv + (size_t)arow * 128 + k0);
                xb = *(const float4*)((const float*)Xv + (size_t)arow * 128 + k0 + 4);
            }
        }
        if (AFFINE) {
            float4 sa = *(const float4*)(scale + k0), sb = *(const float4*)(scale + k0 + 4);
            float4 ha = *(const float4*)(shift + k0), hb = *(const float4*)(shift + k0 + 4);
            xa.x = fmaxf(fmaf(xa.x, sa.x, ha.x), 0.f);
            xa.y = fmaxf(fmaf(xa.y, sa.y, ha.y), 0.f);
            xa.z = fmaxf(fmaf(xa.z, sa.z, ha.z), 0.f);
            xa.w = fmaxf(fmaf(xa.w, sa.w, ha.w), 0.f);
            xb.x = fmaxf(fmaf(xb.x, sb.x, hb.x), 0.f);
            xb.y = fmaxf(fmaf(xb.y, sb.y, hb.y), 0.f);
            xb.z = fmaxf(fmaf(xb.z, sb.z, hb.z), 0.f);
            xb.w = fmaxf(fmaf(xb.w, sb.w, hb.w), 0.f);
        }
        if (WRITEH && rv) {
            nt_store_f4(Hout + (size_t)arow * 128 + k0, xa);
            nt_store_f4(Hout + (size_t)arow * 128 + k0 + 4, xb);
        }
        union { u16 h[8]; bf16x8 v; } ua;
        ua.h[0] = f2bf(xa.x); ua.h[1] = f2bf(xa.y); ua.h[2] = f2bf(xa.z); ua.h[3] = f2bf(xa.w);
        ua.h[4] = f2bf(xb.x); ua.h[5] = f2bf(xb.y); ua.h[6] = f2bf(xb.z); ua.h[7] = f2bf(xb.w);
#pragma unroll
        for (int ct = 0; ct < CT; ++ct) {
            uint4 bv = *(const uint4*)(Wp + ((size_t)(ks * CT + ct) * 64 + lane) * 8);
            bf16x8 b = *(const bf16x8*)&bv;
            acc[ct] = __builtin_amdgcn_mfma_f32_16x16x32_bf16(ua.v, b, acc[ct], 0, 0, 0);
        }
    }
    float dv[4];
#pragma unroll
    for (int reg = 0; reg < 4; ++reg) {
        int r = rowbase + quad * 4 + reg;
        dv[reg] = (r < NNODES) ? dinv[r] : 0.f;
    }
#pragma unroll
    for (int ct = 0; ct < CT; ++ct) {
#pragma unroll
        for (int reg = 0; reg < 4; ++reg) {
            int r = rowbase + quad * 4 + reg;
            if (r < NNODES) Bout[(size_t)r * COUT + ct * 16 + m] = f2bf(dv[reg] * acc[ct][reg]);
        }
    }
}

__device__ __forceinline__ void accq(float (&a)[8], uint4 q, float w) {
    a[0] = fmaf(w, bflo(q.x), a[0]);
    a[1] = fmaf(w, bfhi(q.x), a[1]);
    a[2] = fmaf(w, bflo(q.y), a[2]);
    a[3] = fmaf(w, bfhi(q.y), a[3]);
    a[4] = fmaf(w, bflo(q.z), a[4]);
    a[5] = fmaf(w, bfhi(q.z), a[5]);
    a[6] = fmaf(w, bflo(q.w), a[6]);
    a[7] = fmaf(w, bfhi(q.w), a[7]);
}

// ---------------- Aggregation: v1 lane structure, 4 gathers in flight ----------------
// Out[d][c] = dinv[d]*(B[d][c] + sum_s B[s][c]) + bias[c]; logical index 0 = self-loop.
// 16-lane channel groups (c16), 4 edge-slot groups (g); it+=16 with 4 independent
// uint4 gathers per lane per iteration (serial chain 3 iters -> 2 at mean L=17).
// OUTB: store Out as bf16. Output stores nontemporal; colsrc loads normal (L1-cached,
// they sit on the gather address chain).

template <bool STATS, bool OUTB>
__global__ __launch_bounds__(256) void k_agg128v(const u16* __restrict__ Bm, const float* __restrict__ dinv,
                                                 const int* __restrict__ rowptr, const int* __restrict__ colsrc,
                                                 const float* __restrict__ bias, void* __restrict__ Outv,
                                                 float* __restrict__ slots) {
    __shared__ float sO[4][128];
    const int wave = threadIdx.x >> 6;
    const int node = blockIdx.x * 4 + wave;
    const int lane = threadIdx.x & 63;
    const int g = lane >> 4;     // edge slot within gather group
    const int c16 = lane & 15;   // channel block: channels c16*8 .. +7
    const uint4* Bq = (const uint4*)Bm;
    float a0[8], a1[8];
#pragma unroll
    for (int j = 0; j < 8; ++j) { a0[j] = 0.f; a1[j] = 0.f; }
    const int beg = rowptr[node];
    const int L = rowptr[node + 1] - beg + 1;  // edges + self
    for (int it = 0; it < L; it += 16) {
        int i0 = it + g, i1 = it + 4 + g, i2 = it + 8 + g, i3 = it + 12 + g;
        float w0 = (i0 < L) ? 1.f : 0.f;
        float w1 = (i1 < L) ? 1.f : 0.f;
        float w2 = (i2 < L) ? 1.f : 0.f;
        float w3 = (i3 < L) ? 1.f : 0.f;
        i0 = min(i0, L - 1);
        i1 = min(i1, L - 1);
        i2 = min(i2, L - 1);
        i3 = min(i3, L - 1);
        int s0 = colsrc[beg + max(i0, 1) - 1];
        int s1 = colsrc[beg + max(i1, 1) - 1];
        int s2 = colsrc[beg + max(i2, 1) - 1];
        int s3 = colsrc[beg + max(i3, 1) - 1];
        if (i0 == 0) s0 = node;  // self (only it==0, g==0)
        uint4 q0 = Bq[(size_t)s0 * 16 + c16];
        uint4 q1 = Bq[(size_t)s1 * 16 + c16];
        uint4 q2 = Bq[(size_t)s2 * 16 + c16];
        uint4 q3 = Bq[(size_t)s3 * 16 + c16];
        accq(a0, q0, w0);
        accq(a1, q1, w1);
        accq(a0, q2, w2);
        accq(a1, q3, w3);
    }
    const float dv = dinv[node];
    float o[8];
#pragma unroll
    for (int j = 0; j < 8; ++j) {
        float s = a0[j] + a1[j];
        s += __shfl_xor(s, 16);
        s += __shfl_xor(s, 32);
        o[j] = dv * s + bias[c16 * 8 + j];
    }
    if (g == 0) {
        if (OUTB) {
            u16* OutB = (u16*)Outv;
            union { u32 w[4]; uint4 q; } p;
            p.w[0] = (u32)f2bf(o[0]) | ((u32)f2bf(o[1]) << 16);
            p.w[1] = (u32)f2bf(o[2]) | ((u32)f2bf(o[3]) << 16);
            p.w[2] = (u32)f2bf(o[4]) | ((u32)f2bf(o[5]) << 16);
            p.w[3] = (u32)f2bf(o[6]) | ((u32)f2bf(o[7]) << 16);
            nt_store_u4(OutB + (size_t)node * 128 + c16 * 8, p.q);
        } else {
            float* Out = (float*)Outv;
            nt_store_f4(Out + (size_t)node * 128 + c16 * 8, make_float4(o[0], o[1], o[2], o[3]));
            nt_store_f4(Out + (size_t)node * 128 + c16 * 8 + 4, make_float4(o[4], o[5], o[6], o[7]));
        }
        if (STATS) {
#pragma unroll
            for (int j = 0; j < 8; ++j) sO[wave][c16 * 8 + j] = o[j];
        }
    }
    if (STATS) {
        __syncthreads();
        if (threadIdx.x < 128) {
            float s = 0.f, q = 0.f;
#pragma unroll
            for (int wv = 0; wv < 4; ++wv) {
                float v = sO[wv][threadIdx.x];
                s += v;
                q += v * v;
            }
            float* slot = slots + (size_t)(blockIdx.x & (NSLOT - 1)) * 256;
            atomicAdd(&slot[threadIdx.x], s);
            atomicAdd(&slot[128 + threadIdx.x], q);
        }
    }
}

__global__ __launch_bounds__(256) void k_agg64v(const u16* __restrict__ Bm, const float* __restrict__ dinv,
                                                const int* __restrict__ rowptr, const int* __restrict__ colsrc,
                                                const float* __restrict__ bias, float* __restrict__ Out) {
    const int node = blockIdx.x * 4 + (threadIdx.x >> 6);
    const int lane = threadIdx.x & 63;
    const int g = lane >> 3;    // 0..7 edge slots
    const int c8 = lane & 7;    // channels c8*8 .. +7
    const uint4* Bq = (const uint4*)Bm;
    float a0[8], a1[8];
#pragma unroll
    for (int j = 0; j < 8; ++j) { a0[j] = 0.f; a1[j] = 0.f; }
    const int beg = rowptr[node];
    const int L = rowptr[node + 1] - beg + 1;
    for (int it = 0; it < L; it += 16) {
        int i0 = it + g, i1 = it + 8 + g;
        float w0 = (i0 < L) ? 1.f : 0.f;
        float w1 = (i1 < L) ? 1.f : 0.f;
        i0 = min(i0, L - 1);
        i1 = min(i1, L - 1);
        int s0 = colsrc[beg + max(i0, 1) - 1];
        int s1 = colsrc[beg + max(i1, 1) - 1];
        if (i0 == 0) s0 = node;
        uint4 q0 = Bq[(size_t)s0 * 8 + c8];
        uint4 q1 = Bq[(size_t)s1 * 8 + c8];
        accq(a0, q0, w0);
        accq(a1, q1, w1);
    }
    const float dv = dinv[node];
    float o[8];
#pragma unroll
    for (int j = 0; j < 8; ++j) {
        float s = a0[j] + a1[j];
        s += __shfl_xor(s, 8);
        s += __shfl_xor(s, 16);
        s += __shfl_xor(s, 32);
        o[j] = dv * s + bias[c8 * 8 + j];
    }
    if (g == 0) {
        nt_store_f4(Out + (size_t)node * 64 + c8 * 8, make_float4(o[0], o[1], o[2], o[3]));
        nt_store_f4(Out + (size_t)node * 64 + c8 * 8 + 4, make_float4(o[4], o[5], o[6], o[7]));
    }
}

// ---------------- BN finalize: reduce slots -> scale/shift (256 threads, 2-way split) ----------------

__global__ __launch_bounds__(256) void k_bn_final(const float* __restrict__ slots, const float* __restrict__ g,
                                                  const float* __restrict__ be, float* __restrict__ scale,
                                                  float* __restrict__ shift) {
    __shared__ float reds[256], redq[256];
    int t = threadIdx.x;       // 256 threads
    int c = t & 127, h = t >> 7;
    float s = 0.f, q = 0.f;
    for (int k = h * (NSLOT / 2); k < (h + 1) * (NSLOT / 2); ++k) {
        s += slots[(size_t)k * 256 + c];
        q += slots[(size_t)k * 256 + 128 + c];
    }
    reds[t] = s;
    redq[t] = q;
    __syncthreads();
    if (t < 128) {
        s = reds[t] + reds[t + 128];
        q = redq[t] + redq[t + 128];
        float mean = s * (1.0f / NNODES);
        float var = q * (1.0f / NNODES) - mean * mean;
        float istd = rsqrtf(var + EPSBN);
        float sc = g[t] * istd;
        scale[t] = sc;
        shift[t] = be[t] - sc * mean;
    }
}

// ---------------- launch ----------------

extern "C" void kernel_launch(void* const* d_in, const int* in_sizes, int n_in,
                              void* d_out, int out_size, void* d_ws, size_t ws_size,
                              hipStream_t stream) {
    const float* x   = (const float*)d_in[0];
    const float* W1  = (const float*)d_in[1];
    const float* b1  = (const float*)d_in[2];
    const float* g1  = (const float*)d_in[3];
    const float* be1 = (const float*)d_in[4];
    const float* W2  = (const float*)d_in[5];
    const float* b2  = (const float*)d_in[6];
    const float* g2  = (const float*)d_in[7];
    const float* be2 = (const float*)d_in[8];
    const float* W3  = (const float*)d_in[9];
    const float* b3  = (const float*)d_in[10];
    const int* ei    = (const int*)d_in[11];

    float* out_h = (float*)d_out;                        // [N,128] h2
    float* out_o = (float*)d_out + (size_t)NNODES * 128; // [N,64]  conv3 out

    char* w = (char*)d_ws;
    u16* A16 = (u16*)w;        w += (size_t)NNODES * 128 * 2;   // bf16 post-agg activations
    u16* Bm = (u16*)w;         w += (size_t)NNODES * 128 * 2;   // bf16 messages
    float* dinv = (float*)w;   w += (size_t)NNODES * 4;
    int* rowptr = (int*)w;     w += (size_t)(NNODES + 32) * 4;
    int* colsrc = (int*)w;     w += (size_t)(NEDGES + 8) * 4;   // +pad for clamped tail reads
    int* bbase = (int*)w;      w += (NBKT + 4) * 4;
    int* btot = (int*)w;       w += (NBKT + 4) * 4;
    float* slots1 = (float*)w; w += (size_t)NSLOT * 256 * 4;
    float* slots2 = (float*)w; w += (size_t)NSLOT * 256 * 4;
    float* scale = (float*)w;  w += 128 * 4;
    float* shift = (float*)w;  w += 128 * 4;
    u16* Wp1 = (u16*)w;        w += 128 * 128 * 2;
    u16* Wp2 = (u16*)w;        w += 128 * 128 * 2;
    u16* Wp3 = (u16*)w;        w += 128 * 64 * 2;

    // Build-phase scratch aliased onto buffers dead until layer 1:
    u32* rec  = (u32*)A16;                      // [NEDGES] (25.6MB >= 6.4MB needed)
    int* histT = (int*)Bm;                      // [NBKT*NCHUNK]
    int* offT  = (int*)Bm + NBKT * NCHUNK;      // [NBKT*NCHUNK]

    hipMemsetAsync(slots1, 0, (size_t)2 * NSLOT * 256 * 4, stream);

    k_packW_all<<<20, 256, 0, stream>>>(W1, W2, W3, Wp1, Wp2, Wp3);

    // CSR build
    k_hist<<<NCHUNK, 256, 0, stream>>>(ei, histT);
    k_bsum<<<NBKT, 256, 0, stream>>>(histT, btot);
    k_bbase2<<<1, 256, 0, stream>>>(btot, bbase, rowptr);
    k_bscan<<<NBKT, 256, 0, stream>>>(histT, bbase, offT);
    k_scatter<<<NCHUNK, 256, 0, stream>>>(ei, offT, rec);
    k_bfill<<<NBKT, 256, 0, stream>>>(rec, bbase, rowptr, dinv, colsrc);

    const int GB = (NNODES + 63) / 64;   // 1563
    const int AB = NNODES / 4;           // 25000

    // Layer 1: x (fp32) -> Bm -> A16 bf16 (+stats1)
    k_mfma_gemm<128, false, false, false><<<GB, 256, 0, stream>>>(x, Wp1, dinv, nullptr, nullptr, Bm, nullptr);
    k_agg128v<true, true><<<AB, 256, 0, stream>>>(Bm, dinv, rowptr, colsrc, b1, A16, slots1);
    k_bn_final<<<1, 256, 0, stream>>>(slots1, g1, be1, scale, shift);

    // Layer 2: A16 bf16 (BN1+ReLU inline) -> Bm -> A16 bf16 (+stats2)
    k_mfma_gemm<128, true, false, true><<<GB, 256, 0, stream>>>(A16, Wp2, dinv, scale, shift, Bm, nullptr);
    k_agg128v<true, true><<<AB, 256, 0, stream>>>(Bm, dinv, rowptr, colsrc, b2, A16, slots2);
    k_bn_final<<<1, 256, 0, stream>>>(slots2, g2, be2, scale, shift);

    // Layer 3: A16 bf16 (BN2+ReLU inline, h2 written fp32 as byproduct) -> Bm64 -> out_o
    k_mfma_gemm<64, true, true, true><<<GB, 256, 0, stream>>>(A16, Wp3, dinv, scale, shift, Bm, out_h);
    k_agg64v<<<AB, 256, 0, stream>>>(Bm, dinv, rowptr, colsrc, b3, out_o);
}